// Round 7
// baseline (348.820 us; speedup 1.0000x reference)
//
#include <hip/hip_runtime.h>
#include <hip/hip_fp16.h>

typedef _Float16 f16;
typedef _Float16 f16x8 __attribute__((ext_vector_type(8)));
typedef float f32x4 __attribute__((ext_vector_type(4)));

#define BB 4
#define TT 16
#define HH 64
#define WW 64
#define CC 32
#define FF 64
#define GG 256  // 4F gates

__device__ __forceinline__ float hsig(float z) {
    return fminf(fmaxf(0.2f * z + 0.5f, 0.f), 1.f);
}
__device__ __forceinline__ float tanh_fast(float x) {
    return 1.f - 2.f / (__expf(2.f * x) + 1.f);
}

// ---------------- LayerNorm over C=32: fp32 in -> fp16 out ----------------
__global__ void ln_kernel(const float* __restrict__ x,
                          const float* __restrict__ gamma,
                          const float* __restrict__ beta,
                          f16* __restrict__ xn) {
    __shared__ float sg[CC], sb[CC];
    if (threadIdx.x < CC) sg[threadIdx.x] = gamma[threadIdx.x];
    else if (threadIdx.x < 2 * CC) sb[threadIdx.x - CC] = beta[threadIdx.x - CC];
    __syncthreads();
    int q = blockIdx.x * 256 + threadIdx.x;  // pixel < B*T*H*W = 262144
    const float* xp = x + (size_t)q * CC;
    float v[CC];
    float s = 0.f, s2 = 0.f;
#pragma unroll
    for (int c = 0; c < CC; c += 4) {
        float4 t4 = *(const float4*)(xp + c);
        v[c] = t4.x; v[c + 1] = t4.y; v[c + 2] = t4.z; v[c + 3] = t4.w;
        s += t4.x + t4.y + t4.z + t4.w;
        s2 += t4.x * t4.x + t4.y * t4.y + t4.z * t4.z + t4.w * t4.w;
    }
    float mu = s * (1.f / CC);
    float var = s2 * (1.f / CC) - mu * mu;
    float rs = rsqrtf(var + 1e-3f);
    f16 o[CC];
#pragma unroll
    for (int c = 0; c < CC; c++)
        o[c] = (f16)((v[c] - mu) * rs * sg[c] + sb[c]);
    f16x8* d = (f16x8*)(xn + (size_t)q * CC);
#pragma unroll
    for (int c = 0; c < 4; c++) d[c] = *(f16x8*)&o[c * 8];
}

// ------- Weight transpose: wcat[g][0..288)=Wx taps, [288..864)=Wh taps (k contig) -------
__global__ void wprep_kernel(const float* __restrict__ wx, const float* __restrict__ wh,
                             f16* __restrict__ wcat) {
    int e = blockIdx.x * 256 + threadIdx.x;
    if (e < 9 * CC * GG) {                    // 73728: Wx [tap][c][g] -> [g][tap*32+c]
        int g = e & 255, k = e >> 8;
        wcat[g * 864 + k] = (f16)wx[e];
    } else {
        e -= 9 * CC * GG;
        if (e < 9 * FF * GG) {                // 147456: Wh [tap][f][g] -> [g][288+tap*64+f]
            int g = e & 255, k = e >> 8;
            wcat[g * 864 + 288 + k] = (f16)wh[e];
        }
    }
}

// ---------------- Fused step: z = conv(xn,Wx)+conv(h,Wh)+b; gates; state; pool ----------------
// Grid: 1024 = 256 px-tiles x 4 fch-quarters. Block: 128 (2 waves) -> 4 blocks/CU, 2 waves/SIMD.
// Both waves cover 64 px x 64 gates (4 M x 4 cls, acc[4][4]); wave ks takes K-chunks of its
// parity (barrier-free K-split: ks0 even 14, ks1 odd 13). End: balanced register exchange via
// LDS (red[reg][tid], conflict-free b32) -> wave ks epilogues M-tiles {2ks,2ks+1}.
// B-frags streamed L2->VGPR (compile-time chunk offsets); A-frags from LDS patches.
__global__ __launch_bounds__(128, 2)
void step_kernel(const f16* __restrict__ xn, const f16* __restrict__ wcat,
                 const float* __restrict__ bs,
                 float* __restrict__ cst, f16* __restrict__ hs,
                 float* __restrict__ out, int t) {
    __shared__ __align__(16) f16 smem[11200];        // 22.4 KB
    f16* xpatch = smem;                              // [0,4000) stride 40
    f16* hpatch = smem + 4000;                       // [4000,11200) stride 72
    float* red = (float*)smem;                       // alias [0,16384)B: 32 x 128 f32
    f16* hstage = smem + 8192;                       // alias [16384,19456)B: 64px x 24

    int tile = blockIdx.x >> 2, q = blockIdx.x & 3;  // q = fch quarter
    int bb = tile >> 6, ty = (tile >> 3) & 7, tx = tile & 7;
    int tid = threadIdx.x;
    int lane = tid & 63, ks = tid >> 6;
    int quad = lane >> 4, noff = lane & 15;

    int rslot = t & 1;
    const f16* hr = hs + (size_t)rslot * (BB * HH * WW * FF);
    f16* hw = hs + (size_t)(1 - rslot) * (BB * HH * WW * FF);
    const f16* xslice = xn + (size_t)(bb * TT + t) * (HH * WW) * CC;

    // ---- stage patches (zero-padded borders) ----
    {
        f16x8 z = {0, 0, 0, 0, 0, 0, 0, 0};
        for (int j = tid; j < 200; j += 128) {   // xpatch: 100px x 32ch
            int pix = j >> 1, part = j & 1;
            int py = pix / 10, px = pix % 10;
            int y = ty * 8 - 1 + py, x = tx * 8 - 1 + px;
            f16x8* d = (f16x8*)&xpatch[pix * 40 + part * 16];
            if (y >= 0 && y < HH && x >= 0 && x < WW) {
                const f16x8* s = (const f16x8*)(xslice + ((size_t)y * WW + x) * CC + part * 16);
                d[0] = s[0]; d[1] = s[1];
            } else { d[0] = z; d[1] = z; }
        }
        for (int j = tid; j < 200; j += 128) {   // hpatch: 100px x 64ch
            int pix = j >> 1, part = j & 1;
            int py = pix / 10, px = pix % 10;
            int y = ty * 8 - 1 + py, x = tx * 8 - 1 + px;
            f16x8* d = (f16x8*)&hpatch[pix * 72 + part * 32];
            if (y >= 0 && y < HH && x >= 0 && x < WW) {
                const f16x8* s = (const f16x8*)(hr + ((size_t)(bb * HH + y) * WW + x) * FF + part * 32);
                d[0] = s[0]; d[1] = s[1]; d[2] = s[2]; d[3] = s[3];
            } else { d[0] = z; d[1] = z; d[2] = z; d[3] = z; }
        }
    }

    // ---- c-state load (coalesced, private layout; wave ks owns M-tiles {2ks,2ks+1}) ----
    size_t cbase = (size_t)blockIdx.x * 1024 + (size_t)ks * 512 + lane * 8;
    f32x4 cs[2];
    cs[0] = (f32x4){0.f, 0.f, 0.f, 0.f};
    cs[1] = cs[0];
    if (t > 0) {
        cs[0] = *(const f32x4*)(cst + cbase);
        cs[1] = *(const f32x4*)(cst + cbase + 4);
    }

    int fch = (q << 4) + noff;  // f-channel in [0,64), same for both waves
    float b_i = bs[fch], b_f = bs[64 + fch], b_c = bs[128 + fch], b_o = bs[192 + fch];

    // B-frag base pointers (chunk offsets become compile-time immediates)
    const f16* bbase[4];
#pragma unroll
    for (int cls = 0; cls < 4; cls++)
        bbase[cls] = wcat + (size_t)((cls << 6) + fch) * 864 + (quad << 3);

    int ab[4];
#pragma unroll
    for (int mt = 0; mt < 4; mt++) {
        int m = (mt << 4) + noff;
        ab[mt] = (m >> 3) * 10 + (m & 7);
    }

    f32x4 acc[4][4];
#pragma unroll
    for (int i = 0; i < 4; i++)
#pragma unroll
        for (int j = 0; j < 4; j++) acc[i][j] = (f32x4){0.f, 0.f, 0.f, 0.f};

    __syncthreads();  // patches ready

#define DO_CHUNK(c)                                                                        \
    {                                                                                      \
        const bool isx = (c) < 9;                                                          \
        const int tap = isx ? (c) : (((c) - 9) >> 1);                                      \
        const int coff = isx ? 0 : ((((c) - 9) & 1) << 5);                                 \
        const int dy = tap / 3, dx = tap % 3;                                              \
        const f16* ap = isx ? xpatch : hpatch;                                             \
        const int stride = isx ? 40 : 72;                                                  \
        f16x8 bf[4], a[4];                                                                 \
        _Pragma("unroll")                                                                  \
        for (int cls = 0; cls < 4; cls++) bf[cls] = *(const f16x8*)(bbase[cls] + (c) * 32);\
        _Pragma("unroll")                                                                  \
        for (int mt = 0; mt < 4; mt++)                                                     \
            a[mt] = *(const f16x8*)&ap[(ab[mt] + dy * 10 + dx) * stride + coff + (quad << 3)]; \
        _Pragma("unroll")                                                                  \
        for (int cls = 0; cls < 4; cls++)                                                  \
            _Pragma("unroll")                                                              \
            for (int mt = 0; mt < 4; mt++)                                                 \
                acc[mt][cls] = __builtin_amdgcn_mfma_f32_16x16x32_f16(a[mt], bf[cls], acc[mt][cls], 0, 0, 0); \
    }

    if (ks == 0) {
#pragma unroll
        for (int ci = 0; ci < 14; ci++) DO_CHUNK(2 * ci);
    } else {
#pragma unroll
        for (int ci = 0; ci < 13; ci++) DO_CHUNK(2 * ci + 1);
    }
#undef DO_CHUNK

    __syncthreads();  // all patch reads done (red aliases patches)

    // ---- balanced exchange: wave ks sends the OTHER half's partials ----
    if (ks == 0) {
#pragma unroll
        for (int mtl = 0; mtl < 2; mtl++)
#pragma unroll
            for (int cls = 0; cls < 4; cls++)
#pragma unroll
                for (int r = 0; r < 4; r++)
                    red[(((mtl << 2) + cls) * 4 + r) * 128 + tid] = acc[2 + mtl][cls][r];
    } else {
#pragma unroll
        for (int mtl = 0; mtl < 2; mtl++)
#pragma unroll
            for (int cls = 0; cls < 4; cls++)
#pragma unroll
                for (int r = 0; r < 4; r++)
                    red[(((mtl << 2) + cls) * 4 + r) * 128 + tid] = acc[mtl][cls][r];
    }
    __syncthreads();

    f32x4 own[2][4];
    if (ks == 0) {
#pragma unroll
        for (int mtl = 0; mtl < 2; mtl++)
#pragma unroll
            for (int cls = 0; cls < 4; cls++) {
                f32x4 v = acc[mtl][cls];
#pragma unroll
                for (int r = 0; r < 4; r++)
                    v[r] += red[(((mtl << 2) + cls) * 4 + r) * 128 + (tid ^ 64)];
                own[mtl][cls] = v;
            }
    } else {
#pragma unroll
        for (int mtl = 0; mtl < 2; mtl++)
#pragma unroll
            for (int cls = 0; cls < 4; cls++) {
                f32x4 v = acc[2 + mtl][cls];
#pragma unroll
                for (int r = 0; r < 4; r++)
                    v[r] += red[(((mtl << 2) + cls) * 4 + r) * 128 + (tid ^ 64)];
                own[mtl][cls] = v;
            }
    }

    // ---- epilogue: gates + state on own 2 M-tiles; h -> hstage; coalesced cst ----
#pragma unroll
    for (int mtl = 0; mtl < 2; mtl++) {
        f32x4 cn4;
#pragma unroll
        for (int r = 0; r < 4; r++) {
            int m = ((ks * 2 + mtl) << 4) + (quad << 2) + r;  // C/D row = quad*4+reg
            float zi = own[mtl][0][r] + b_i;
            float zf = own[mtl][1][r] + b_f;
            float zc = own[mtl][2][r] + b_c;
            float zo = own[mtl][3][r] + b_o;
            float ig = hsig(zi), fg = hsig(zf), og = hsig(zo);
            float cn = fg * cs[mtl][r] + ig * tanh_fast(zc);
            cn4[r] = cn;
            hstage[m * 24 + noff] = (f16)(og * tanh_fast(cn));
        }
        *(f32x4*)(cst + cbase + mtl * 4) = cn4;
    }
    __syncthreads();  // hstage complete

    // coalesced h write: 64 px x 16 f16 (this block's fch quarter)
    {
        int px = tid >> 1, part = tid & 1;
        int y = ty * 8 + (px >> 3), x = tx * 8 + (px & 7);
        f16x8 hv = *(const f16x8*)&hstage[px * 24 + part * 8];
        *(f16x8*)(hw + ((size_t)(bb * HH + y) * WW + x) * FF + (q << 4) + part * 8) = hv;
    }
    // fused 2x2 maxpool: 16 out px x 16 fch -> fp32 out
    {
        int opx = tid >> 3, fp = (tid & 7) * 2;
        int oy2 = opx >> 2, ox2 = opx & 3;
        int p00 = (oy2 * 2) * 8 + ox2 * 2;
        float2 mv;
        mv.x = fmaxf(fmaxf((float)hstage[p00 * 24 + fp], (float)hstage[(p00 + 1) * 24 + fp]),
                     fmaxf((float)hstage[(p00 + 8) * 24 + fp], (float)hstage[(p00 + 9) * 24 + fp]));
        mv.y = fmaxf(fmaxf((float)hstage[p00 * 24 + fp + 1], (float)hstage[(p00 + 1) * 24 + fp + 1]),
                     fmaxf((float)hstage[(p00 + 8) * 24 + fp + 1], (float)hstage[(p00 + 9) * 24 + fp + 1]));
        size_t oidx = ((size_t)((bb * TT + t) * 32 + ty * 4 + oy2) * 32 + tx * 4 + ox2) * 64
                    + (q << 4) + fp;
        *(float2*)(out + oidx) = mv;
    }
}

extern "C" void kernel_launch(void* const* d_in, const int* in_sizes, int n_in,
                              void* d_out, int out_size, void* d_ws, size_t ws_size,
                              hipStream_t stream) {
    const float* x = (const float*)d_in[0];
    const float* gamma = (const float*)d_in[1];
    const float* beta = (const float*)d_in[2];
    const float* wx = (const float*)d_in[3];
    const float* wh = (const float*)d_in[4];
    const float* bs = (const float*)d_in[5];
    float* out = (float*)d_out;

    // workspace layout (16B-aligned); ~25.6 MB
    char* ws = (char*)d_ws;
    f16* xn = (f16*)ws;                        // 16,777,216 B
    f16* wcat = (f16*)(ws + 16777216);         // 256*864*2 = 442,368 B
    float* cst = (float*)(ws + 17219584);      // 4,194,304 B (1024 blocks x 4KB, private)
    f16* hs = (f16*)(ws + 21413888);           // 2 x 2,097,152 B (ping-pong)

    hipMemsetAsync(hs, 0, (size_t)BB * HH * WW * FF * 2, stream);  // h0 = 0 (slot 0)

    ln_kernel<<<1024, 256, 0, stream>>>(x, gamma, beta, xn);
    wprep_kernel<<<864, 256, 0, stream>>>(wx, wh, wcat);
    for (int t = 0; t < TT; t++)
        step_kernel<<<1024, 128, 0, stream>>>(xn, wcat, bs, cst, hs, out, t);
}